// Round 1
// baseline (5891.470 us; speedup 1.0000x reference)
//
#include <hip/hip_runtime.h>
#include <math.h>

// ---------------- problem constants ----------------
constexpr int Bsz  = 2048;
constexpr int Hd   = 256;   // hidden
constexpr int Tst  = 60;    // timesteps
constexpr int ROWS = 8;     // batch rows per block
constexpr int NBLK = Bsz / ROWS;  // 256 blocks
constexpr int NTHR = 256;

// ---------------- workspace layout (floats) ----------------
// W_projT : [386][256]            (k-major, coalesced over units)
// W4C     : [256][256][4]         W_ih0[:,2+k] repacked (k, unit, gate i/f/g/o)
// W40     : [258][256][4]         k<2: W_ih0[:,k] (pos);  k>=2: W_hh0[:,k-2]
// W41     : [512][256][4]         k<256: W_ih1[:,k];      k>=256: W_hh1[:,k-256]
// O1T     : [256][64]             W_out1 transposed
constexpr int OFF_PROJT = 0;
constexpr int N_PROJT   = 386 * 256;                  // 98816
constexpr int OFF_W4C   = OFF_PROJT + N_PROJT;        // 98816
constexpr int N_W4C     = 256 * 256 * 4;              // 262144
constexpr int OFF_W40   = OFF_W4C + N_W4C;            // 360960
constexpr int N_W40     = 258 * 256 * 4;              // 264192
constexpr int OFF_W41   = OFF_W40 + N_W40;            // 625152
constexpr int N_W41     = 512 * 256 * 4;              // 524288
constexpr int OFF_O1T   = OFF_W41 + N_W41;            // 1149440
constexpr int N_O1T     = 256 * 64;                   // 16384
constexpr int WS_FLOATS = OFF_O1T + N_O1T;            // 1165824 (~4.66 MB)

// ---------------- weight repack ----------------
__global__ void prep_kernel(const float* __restrict__ Wproj,
                            const float* __restrict__ Wih0,
                            const float* __restrict__ Whh0,
                            const float* __restrict__ Wih1,
                            const float* __restrict__ Whh1,
                            const float* __restrict__ Wout1,
                            float* __restrict__ ws) {
    int i = blockIdx.x * blockDim.x + threadIdx.x;
    if (i < OFF_W4C) {                       // ProjT: i = k*256+u
        int k = i >> 8, u = i & 255;
        ws[i] = Wproj[u * 386 + k];
    } else if (i < OFF_W40) {                // W4C: j = (k*256+u)*4+g
        int j = i - OFF_W4C;
        int g = j & 3, u = (j >> 2) & 255, k = j >> 10;
        ws[i] = Wih0[(g * 256 + u) * 258 + 2 + k];
    } else if (i < OFF_W41) {                // W40
        int j = i - OFF_W40;
        int g = j & 3, u = (j >> 2) & 255, k = j >> 10;   // k in [0,258)
        ws[i] = (k < 2) ? Wih0[(g * 256 + u) * 258 + k]
                        : Whh0[(g * 256 + u) * 256 + (k - 2)];
    } else if (i < OFF_O1T) {                // W41
        int j = i - OFF_W41;
        int g = j & 3, u = (j >> 2) & 255, k = j >> 10;   // k in [0,512)
        ws[i] = (k < 256) ? Wih1[(g * 256 + u) * 256 + k]
                          : Whh1[(g * 256 + u) * 256 + (k - 256)];
    } else if (i < WS_FLOATS) {              // O1T: j = k*64+m
        int j = i - OFF_O1T;
        int k = j >> 6, m = j & 63;
        ws[i] = Wout1[m * 256 + k];
    }
}

// ---------------- activations ----------------
__device__ __forceinline__ float sigm(float x) {
    return 1.0f / (1.0f + __expf(-x));
}
__device__ __forceinline__ float tanh_(float x) {
    float t = __expf(-2.0f * fabsf(x));
    float r = (1.0f - t) / (1.0f + t);
    return copysignf(r, x);
}

// ---------------- main persistent-row kernel ----------------
__global__ __launch_bounds__(NTHR) void lstm_main(
    const float* __restrict__ env, const float* __restrict__ hist,
    const float* __restrict__ goal, const float* __restrict__ cpos,
    const float* __restrict__ b_proj,
    const float* __restrict__ b_ih0, const float* __restrict__ b_hh0,
    const float* __restrict__ b_ih1, const float* __restrict__ b_hh1,
    const float* __restrict__ b_out1, const float* __restrict__ b_out2,
    const float* __restrict__ Wout2,
    const float* __restrict__ ws, float* __restrict__ out) {

    // LDS: all [k][row] layouts so dot-loops read float4 broadcasts
    __shared__ __align__(16) float xbuf[386 * ROWS];   // ctx_in staged
    __shared__ __align__(16) float ctxL[Hd * ROWS];
    __shared__ __align__(16) float h1L[Hd * ROWS];
    __shared__ __align__(16) float h2L[Hd * ROWS];
    __shared__ __align__(16) float mlpL[ROWS * 64];
    __shared__ __align__(16) float posL[2 * ROWS];

    const int t    = threadIdx.x;        // owned hidden unit
    const int row0 = blockIdx.x * ROWS;  // first global batch row

    const float*  PROJT = ws + OFF_PROJT;
    const float4* W4C   = (const float4*)(ws + OFF_W4C);
    const float4* W40   = (const float4*)(ws + OFF_W40);
    const float4* W41   = (const float4*)(ws + OFF_W41);
    const float*  O1T   = ws + OFF_O1T;

    // ---- stage ctx_in ([k][r]) and initial pos ----
    for (int idx = t; idx < 386 * ROWS; idx += NTHR) {
        int r = idx & 7, k = idx >> 3;
        int gr = row0 + r;
        float v;
        if (k < 256)      v = env[gr * 256 + k];
        else if (k < 384) v = hist[gr * 128 + (k - 256)];
        else              v = goal[gr * 2 + (k - 384)];
        xbuf[k * ROWS + r] = v;
    }
    if (t < 2 * ROWS) {
        int r = t >> 1, o = t & 1;
        posL[o * ROWS + r] = cpos[(row0 + r) * 2 + o];
    }
    __syncthreads();

    // ---- context = ctx_in @ W_proj.T + b_proj ; h1 = h2 = context ----
    {
        float acc[ROWS];
        float bp = b_proj[t];
#pragma unroll
        for (int r = 0; r < ROWS; ++r) acc[r] = bp;
#pragma unroll 2
        for (int k = 0; k < 386; ++k) {
            float w = PROJT[k * Hd + t];
            const float4 xa = *(const float4*)&xbuf[k * ROWS];
            const float4 xb = *(const float4*)&xbuf[k * ROWS + 4];
            float xr[8] = {xa.x, xa.y, xa.z, xa.w, xb.x, xb.y, xb.z, xb.w};
#pragma unroll
            for (int r = 0; r < ROWS; ++r) acc[r] = fmaf(xr[r], w, acc[r]);
        }
#pragma unroll
        for (int r = 0; r < ROWS; ++r) {
            ctxL[t * ROWS + r] = acc[r];
            h1L[t * ROWS + r]  = acc[r];
            h2L[t * ROWS + r]  = acc[r];
        }
    }
    __syncthreads();

    // ---- G0c: constant context contribution to layer-0 gates (+ biases) ----
    float g0i[ROWS], g0f[ROWS], g0g[ROWS], g0o[ROWS];
    {
        float bi = b_ih0[t] + b_hh0[t];
        float bf = b_ih0[256 + t] + b_hh0[256 + t];
        float bg = b_ih0[512 + t] + b_hh0[512 + t];
        float bo = b_ih0[768 + t] + b_hh0[768 + t];
#pragma unroll
        for (int r = 0; r < ROWS; ++r) { g0i[r] = bi; g0f[r] = bf; g0g[r] = bg; g0o[r] = bo; }
#pragma unroll 2
        for (int k = 0; k < Hd; ++k) {
            float4 w = W4C[k * Hd + t];
            const float4 xa = *(const float4*)&ctxL[k * ROWS];
            const float4 xb = *(const float4*)&ctxL[k * ROWS + 4];
            float xr[8] = {xa.x, xa.y, xa.z, xa.w, xb.x, xb.y, xb.z, xb.w};
#pragma unroll
            for (int r = 0; r < ROWS; ++r) {
                g0i[r] = fmaf(xr[r], w.x, g0i[r]);
                g0f[r] = fmaf(xr[r], w.y, g0f[r]);
                g0g[r] = fmaf(xr[r], w.z, g0g[r]);
                g0o[r] = fmaf(xr[r], w.w, g0o[r]);
            }
        }
    }

    // layer-1 biases (per owned unit)
    const float b1i = b_ih1[t] + b_hh1[t];
    const float b1f = b_ih1[256 + t] + b_hh1[256 + t];
    const float b1g = b_ih1[512 + t] + b_hh1[512 + t];
    const float b1o = b_ih1[768 + t] + b_hh1[768 + t];
    const float bm  = b_out1[t & 63];

    float c1[ROWS], c2[ROWS];
#pragma unroll
    for (int r = 0; r < ROWS; ++r) { c1[r] = 0.f; c2[r] = 0.f; }

    // ================= time loop =================
    for (int step = 0; step < Tst; ++step) {
        // ---- Phase A: layer-0 gates = G0c + W_pos@pos + W_hh0@h1 ----
        float ai[ROWS], af[ROWS], ag[ROWS], ao[ROWS];
#pragma unroll
        for (int r = 0; r < ROWS; ++r) { ai[r] = g0i[r]; af[r] = g0f[r]; ag[r] = g0g[r]; ao[r] = g0o[r]; }
#pragma unroll
        for (int k = 0; k < 2; ++k) {
            float4 w = W40[k * Hd + t];
#pragma unroll
            for (int r = 0; r < ROWS; ++r) {
                float x = posL[k * ROWS + r];
                ai[r] = fmaf(x, w.x, ai[r]); af[r] = fmaf(x, w.y, af[r]);
                ag[r] = fmaf(x, w.z, ag[r]); ao[r] = fmaf(x, w.w, ao[r]);
            }
        }
#pragma unroll 2
        for (int k = 0; k < Hd; ++k) {
            float4 w = W40[(k + 2) * Hd + t];
            const float4 xa = *(const float4*)&h1L[k * ROWS];
            const float4 xb = *(const float4*)&h1L[k * ROWS + 4];
            float xr[8] = {xa.x, xa.y, xa.z, xa.w, xb.x, xb.y, xb.z, xb.w};
#pragma unroll
            for (int r = 0; r < ROWS; ++r) {
                ai[r] = fmaf(xr[r], w.x, ai[r]); af[r] = fmaf(xr[r], w.y, af[r]);
                ag[r] = fmaf(xr[r], w.z, ag[r]); ao[r] = fmaf(xr[r], w.w, ao[r]);
            }
        }
        __syncthreads();   // all reads of h1L done
#pragma unroll
        for (int r = 0; r < ROWS; ++r) {
            float iv = sigm(ai[r]), fv = sigm(af[r]);
            float gv = tanh_(ag[r]), ov = sigm(ao[r]);
            c1[r] = fmaf(fv, c1[r], iv * gv);
            h1L[t * ROWS + r] = ov * tanh_(c1[r]);
        }
        __syncthreads();   // new h1 visible

        // ---- Phase B: layer-1 gates = b1 + W_ih1@h1 + W_hh1@h2 ----
#pragma unroll
        for (int r = 0; r < ROWS; ++r) { ai[r] = b1i; af[r] = b1f; ag[r] = b1g; ao[r] = b1o; }
#pragma unroll 2
        for (int k = 0; k < Hd; ++k) {
            float4 w = W41[k * Hd + t];
            const float4 xa = *(const float4*)&h1L[k * ROWS];
            const float4 xb = *(const float4*)&h1L[k * ROWS + 4];
            float xr[8] = {xa.x, xa.y, xa.z, xa.w, xb.x, xb.y, xb.z, xb.w};
#pragma unroll
            for (int r = 0; r < ROWS; ++r) {
                ai[r] = fmaf(xr[r], w.x, ai[r]); af[r] = fmaf(xr[r], w.y, af[r]);
                ag[r] = fmaf(xr[r], w.z, ag[r]); ao[r] = fmaf(xr[r], w.w, ao[r]);
            }
        }
#pragma unroll 2
        for (int k = 0; k < Hd; ++k) {
            float4 w = W41[(Hd + k) * Hd + t];
            const float4 xa = *(const float4*)&h2L[k * ROWS];
            const float4 xb = *(const float4*)&h2L[k * ROWS + 4];
            float xr[8] = {xa.x, xa.y, xa.z, xa.w, xb.x, xb.y, xb.z, xb.w};
#pragma unroll
            for (int r = 0; r < ROWS; ++r) {
                ai[r] = fmaf(xr[r], w.x, ai[r]); af[r] = fmaf(xr[r], w.y, af[r]);
                ag[r] = fmaf(xr[r], w.z, ag[r]); ao[r] = fmaf(xr[r], w.w, ao[r]);
            }
        }
        __syncthreads();   // all reads of h2L done
#pragma unroll
        for (int r = 0; r < ROWS; ++r) {
            float iv = sigm(ai[r]), fv = sigm(af[r]);
            float gv = tanh_(ag[r]), ov = sigm(ao[r]);
            c2[r] = fmaf(fv, c2[r], iv * gv);
            h2L[t * ROWS + r] = ov * tanh_(c2[r]);
        }
        __syncthreads();   // new h2 visible

        // ---- Phase C: mlp = relu(h2 @ W_out1.T + b_out1) ----
        {
            const int m  = t & 63;
            const int r0 = t >> 6;               // handles rows r0 and r0+4
            float a0 = bm, a1 = bm;
#pragma unroll 4
            for (int k = 0; k < Hd; ++k) {
                float w = O1T[k * 64 + m];
                a0 = fmaf(h2L[k * ROWS + r0], w, a0);
                a1 = fmaf(h2L[k * ROWS + r0 + 4], w, a1);
            }
            mlpL[r0 * 64 + m]       = fmaxf(a0, 0.f);
            mlpL[(r0 + 4) * 64 + m] = fmaxf(a1, 0.f);
        }
        __syncthreads();

        // ---- Phase C2: pred = mlp @ W_out2.T + b_out2 ; pos <- pred ----
        if (t < 2 * ROWS) {
            int r = t >> 1, o = t & 1;
            float a = b_out2[o];
#pragma unroll
            for (int k = 0; k < 64; ++k) a = fmaf(mlpL[r * 64 + k], Wout2[o * 64 + k], a);
            posL[o * ROWS + r] = a;
            out[((size_t)(row0 + r) * Tst + step) * 2 + o] = a;
        }
        __syncthreads();
    }
}

// ---------------- launch ----------------
extern "C" void kernel_launch(void* const* d_in, const int* in_sizes, int n_in,
                              void* d_out, int out_size, void* d_ws, size_t ws_size,
                              hipStream_t stream) {
    const float* env    = (const float*)d_in[0];
    const float* hist   = (const float*)d_in[1];
    const float* goal   = (const float*)d_in[2];
    const float* cpos   = (const float*)d_in[3];
    const float* Wproj  = (const float*)d_in[4];
    const float* bproj  = (const float*)d_in[5];
    const float* Wih0   = (const float*)d_in[6];
    const float* Whh0   = (const float*)d_in[7];
    const float* bih0   = (const float*)d_in[8];
    const float* bhh0   = (const float*)d_in[9];
    const float* Wih1   = (const float*)d_in[10];
    const float* Whh1   = (const float*)d_in[11];
    const float* bih1   = (const float*)d_in[12];
    const float* bhh1   = (const float*)d_in[13];
    const float* Wout1  = (const float*)d_in[14];
    const float* bout1  = (const float*)d_in[15];
    const float* Wout2  = (const float*)d_in[16];
    const float* bout2  = (const float*)d_in[17];

    if (ws_size < (size_t)WS_FLOATS * sizeof(float)) return;  // need ~4.7 MB scratch
    float* ws = (float*)d_ws;

    prep_kernel<<<(WS_FLOATS + 255) / 256, 256, 0, stream>>>(
        Wproj, Wih0, Whh0, Wih1, Whh1, Wout1, ws);

    lstm_main<<<NBLK, NTHR, 0, stream>>>(
        env, hist, goal, cpos, bproj, bih0, bhh0, bih1, bhh1,
        bout1, bout2, Wout2, ws, (float*)d_out);
}

// Round 2
// 4410.261 us; speedup vs baseline: 1.3359x; 1.3359x over previous
//
#include <hip/hip_runtime.h>
#include <math.h>

// ---------------- problem constants ----------------
constexpr int Bsz  = 2048;
constexpr int Hd   = 256;   // hidden
constexpr int Tst  = 60;    // timesteps
constexpr int ROWS = 8;     // batch rows per block
constexpr int NBLK = Bsz / ROWS;  // 256 blocks
constexpr int NTHR = 512;   // 2 K-half groups x 256 units

// ---------------- workspace layout (floats) ----------------
// W_projT : [386][256]            (k-major, coalesced over units)
// W4C     : [256][256][4]         W_ih0[:,2+k] repacked (k, unit, gate i/f/g/o)
// W40     : [258][256][4]         k<2: W_ih0[:,k] (pos);  k>=2: W_hh0[:,k-2]
// W41     : [512][256][4]         k<256: W_ih1[:,k];      k>=256: W_hh1[:,k-256]
// O1T     : [256][64]             W_out1 transposed
constexpr int OFF_PROJT = 0;
constexpr int N_PROJT   = 386 * 256;
constexpr int OFF_W4C   = OFF_PROJT + N_PROJT;
constexpr int N_W4C     = 256 * 256 * 4;
constexpr int OFF_W40   = OFF_W4C + N_W4C;
constexpr int N_W40     = 258 * 256 * 4;
constexpr int OFF_W41   = OFF_W40 + N_W40;
constexpr int N_W41     = 512 * 256 * 4;
constexpr int OFF_O1T   = OFF_W41 + N_W41;
constexpr int N_O1T     = 256 * 64;
constexpr int WS_FLOATS = OFF_O1T + N_O1T;   // ~4.66 MB

// ---------------- weight repack ----------------
__global__ void prep_kernel(const float* __restrict__ Wproj,
                            const float* __restrict__ Wih0,
                            const float* __restrict__ Whh0,
                            const float* __restrict__ Wih1,
                            const float* __restrict__ Whh1,
                            const float* __restrict__ Wout1,
                            float* __restrict__ ws) {
    int i = blockIdx.x * blockDim.x + threadIdx.x;
    if (i < OFF_W4C) {                       // ProjT
        int k = i >> 8, u = i & 255;
        ws[i] = Wproj[u * 386 + k];
    } else if (i < OFF_W40) {                // W4C
        int j = i - OFF_W4C;
        int g = j & 3, u = (j >> 2) & 255, k = j >> 10;
        ws[i] = Wih0[(g * 256 + u) * 258 + 2 + k];
    } else if (i < OFF_W41) {                // W40
        int j = i - OFF_W40;
        int g = j & 3, u = (j >> 2) & 255, k = j >> 10;
        ws[i] = (k < 2) ? Wih0[(g * 256 + u) * 258 + k]
                        : Whh0[(g * 256 + u) * 256 + (k - 2)];
    } else if (i < OFF_O1T) {                // W41
        int j = i - OFF_W41;
        int g = j & 3, u = (j >> 2) & 255, k = j >> 10;
        ws[i] = (k < 256) ? Wih1[(g * 256 + u) * 256 + k]
                          : Whh1[(g * 256 + u) * 256 + (k - 256)];
    } else if (i < WS_FLOATS) {              // O1T
        int j = i - OFF_O1T;
        int k = j >> 6, m = j & 63;
        ws[i] = Wout1[m * 256 + k];
    }
}

// ---------------- activations ----------------
__device__ __forceinline__ float sigm(float x) {
    return 1.0f / (1.0f + __expf(-x));
}
__device__ __forceinline__ float tanh_(float x) {
    float t = __expf(-2.0f * fabsf(x));
    float r = (1.0f - t) / (1.0f + t);
    return copysignf(r, x);
}

// ---------------- main persistent-row kernel ----------------
// 512 threads: u = t&255 (owned hidden unit), kh = t>>8 (K-half).
// Each thread accumulates 4 gates x 8 rows over half the K range;
// kh=1 dumps partials to redL, kh=0 reduces + owns cell state.
__global__ __launch_bounds__(NTHR) void lstm_main(
    const float* __restrict__ env, const float* __restrict__ hist,
    const float* __restrict__ goal, const float* __restrict__ cpos,
    const float* __restrict__ b_proj,
    const float* __restrict__ b_ih0, const float* __restrict__ b_hh0,
    const float* __restrict__ b_ih1, const float* __restrict__ b_hh1,
    const float* __restrict__ b_out1, const float* __restrict__ b_out2,
    const float* __restrict__ Wout2,
    const float* __restrict__ ws, float* __restrict__ out) {

    __shared__ __align__(16) float xbuf[386 * ROWS];
    __shared__ __align__(16) float ctxL[Hd * ROWS];
    __shared__ __align__(16) float h1L[Hd * ROWS];
    __shared__ __align__(16) float h2L[Hd * ROWS];
    __shared__ __align__(16) float mlpL[ROWS * 64];
    __shared__ __align__(16) float posL[2 * ROWS];
    __shared__ __align__(16) float4 redL[8 * 256];   // [chunk][unit]

    const int t    = threadIdx.x;
    const int u    = t & 255;
    const int kh   = t >> 8;           // 0 or 1
    const int row0 = blockIdx.x * ROWS;

    const float*  PROJT = ws + OFF_PROJT;
    const float4* W4C   = (const float4*)(ws + OFF_W4C);
    const float4* W40   = (const float4*)(ws + OFF_W40);
    const float4* W41   = (const float4*)(ws + OFF_W41);
    const float*  O1T   = ws + OFF_O1T;

    // ---- stage ctx_in ([k][r]) and initial pos ----
    for (int idx = t; idx < 386 * ROWS; idx += NTHR) {
        int r = idx & 7, k = idx >> 3;
        int gr = row0 + r;
        float v;
        if (k < 256)      v = env[gr * 256 + k];
        else if (k < 384) v = hist[gr * 128 + (k - 256)];
        else              v = goal[gr * 2 + (k - 384)];
        xbuf[k * ROWS + r] = v;
    }
    if (t < 2 * ROWS) {
        int r = t >> 1, o = t & 1;
        posL[o * ROWS + r] = cpos[(row0 + r) * 2 + o];
    }
    __syncthreads();

    // ---- context = ctx_in @ W_proj.T + b_proj (kh=0 group only, one-time) ----
    if (kh == 0) {
        float acc[ROWS];
        float bp = b_proj[u];
#pragma unroll
        for (int r = 0; r < ROWS; ++r) acc[r] = bp;
#pragma unroll 2
        for (int k = 0; k < 386; ++k) {
            float w = PROJT[k * Hd + u];
            const float4 xa = *(const float4*)&xbuf[k * ROWS];
            const float4 xb = *(const float4*)&xbuf[k * ROWS + 4];
            float xr[8] = {xa.x, xa.y, xa.z, xa.w, xb.x, xb.y, xb.z, xb.w};
#pragma unroll
            for (int r = 0; r < ROWS; ++r) acc[r] = fmaf(xr[r], w, acc[r]);
        }
#pragma unroll
        for (int r = 0; r < ROWS; ++r) {
            ctxL[u * ROWS + r] = acc[r];
            h1L[u * ROWS + r]  = acc[r];
            h2L[u * ROWS + r]  = acc[r];
        }
    }
    __syncthreads();

    // ---- G0c partial: this K-half's context contribution to layer-0 gates ----
    float g0i[ROWS], g0f[ROWS], g0g[ROWS], g0o[ROWS];
    {
        float bi = 0.f, bf = 0.f, bg = 0.f, bo = 0.f;
        if (kh == 0) {   // biases counted once
            bi = b_ih0[u] + b_hh0[u];
            bf = b_ih0[256 + u] + b_hh0[256 + u];
            bg = b_ih0[512 + u] + b_hh0[512 + u];
            bo = b_ih0[768 + u] + b_hh0[768 + u];
        }
#pragma unroll
        for (int r = 0; r < ROWS; ++r) { g0i[r] = bi; g0f[r] = bf; g0g[r] = bg; g0o[r] = bo; }
        const int kb = kh << 7;   // 0 or 128
#pragma unroll 4
        for (int k = 0; k < 128; ++k) {
            float4 w = W4C[(kb + k) * Hd + u];
            const float4 xa = *(const float4*)&ctxL[(kb + k) * ROWS];
            const float4 xb = *(const float4*)&ctxL[(kb + k) * ROWS + 4];
            float xr[8] = {xa.x, xa.y, xa.z, xa.w, xb.x, xb.y, xb.z, xb.w};
#pragma unroll
            for (int r = 0; r < ROWS; ++r) {
                g0i[r] = fmaf(xr[r], w.x, g0i[r]);
                g0f[r] = fmaf(xr[r], w.y, g0f[r]);
                g0g[r] = fmaf(xr[r], w.z, g0g[r]);
                g0o[r] = fmaf(xr[r], w.w, g0o[r]);
            }
        }
    }

    // layer-1 biases (kh=0 only; kh=1 partials start at 0)
    const float b1i = (kh == 0) ? b_ih1[u] + b_hh1[u] : 0.f;
    const float b1f = (kh == 0) ? b_ih1[256 + u] + b_hh1[256 + u] : 0.f;
    const float b1g = (kh == 0) ? b_ih1[512 + u] + b_hh1[512 + u] : 0.f;
    const float b1o = (kh == 0) ? b_ih1[768 + u] + b_hh1[768 + u] : 0.f;
    const float bm  = b_out1[t & 63];

    float c1[ROWS], c2[ROWS];
#pragma unroll
    for (int r = 0; r < ROWS; ++r) { c1[r] = 0.f; c2[r] = 0.f; }

    // ================= time loop =================
    for (int step = 0; step < Tst; ++step) {
        float ai[ROWS], af[ROWS], ag[ROWS], ao[ROWS];

        // ---- Phase A partials: G0c + (kh0: W_pos@pos + W_hh0@h1[0:128)) + (kh1: W_hh0@h1[128:256)) ----
#pragma unroll
        for (int r = 0; r < ROWS; ++r) { ai[r] = g0i[r]; af[r] = g0f[r]; ag[r] = g0g[r]; ao[r] = g0o[r]; }
        if (kh == 0) {
#pragma unroll
            for (int k = 0; k < 2; ++k) {
                float4 w = W40[k * Hd + u];
#pragma unroll
                for (int r = 0; r < ROWS; ++r) {
                    float x = posL[k * ROWS + r];
                    ai[r] = fmaf(x, w.x, ai[r]); af[r] = fmaf(x, w.y, af[r]);
                    ag[r] = fmaf(x, w.z, ag[r]); ao[r] = fmaf(x, w.w, ao[r]);
                }
            }
        }
        {
            const int kb = kh << 7;
#pragma unroll 4
            for (int k = 0; k < 128; ++k) {
                float4 w = W40[(2 + kb + k) * Hd + u];
                const float4 xa = *(const float4*)&h1L[(kb + k) * ROWS];
                const float4 xb = *(const float4*)&h1L[(kb + k) * ROWS + 4];
                float xr[8] = {xa.x, xa.y, xa.z, xa.w, xb.x, xb.y, xb.z, xb.w};
#pragma unroll
                for (int r = 0; r < ROWS; ++r) {
                    ai[r] = fmaf(xr[r], w.x, ai[r]); af[r] = fmaf(xr[r], w.y, af[r]);
                    ag[r] = fmaf(xr[r], w.z, ag[r]); ao[r] = fmaf(xr[r], w.w, ao[r]);
                }
            }
        }
        if (kh == 1) {
            redL[0 * 256 + u] = make_float4(ai[0], ai[1], ai[2], ai[3]);
            redL[1 * 256 + u] = make_float4(ai[4], ai[5], ai[6], ai[7]);
            redL[2 * 256 + u] = make_float4(af[0], af[1], af[2], af[3]);
            redL[3 * 256 + u] = make_float4(af[4], af[5], af[6], af[7]);
            redL[4 * 256 + u] = make_float4(ag[0], ag[1], ag[2], ag[3]);
            redL[5 * 256 + u] = make_float4(ag[4], ag[5], ag[6], ag[7]);
            redL[6 * 256 + u] = make_float4(ao[0], ao[1], ao[2], ao[3]);
            redL[7 * 256 + u] = make_float4(ao[4], ao[5], ao[6], ao[7]);
        }
        __syncthreads();                       // b1: partials in redL
        if (kh == 0) {
            float4 q;
            q = redL[0 * 256 + u]; ai[0] += q.x; ai[1] += q.y; ai[2] += q.z; ai[3] += q.w;
            q = redL[1 * 256 + u]; ai[4] += q.x; ai[5] += q.y; ai[6] += q.z; ai[7] += q.w;
            q = redL[2 * 256 + u]; af[0] += q.x; af[1] += q.y; af[2] += q.z; af[3] += q.w;
            q = redL[3 * 256 + u]; af[4] += q.x; af[5] += q.y; af[6] += q.z; af[7] += q.w;
            q = redL[4 * 256 + u]; ag[0] += q.x; ag[1] += q.y; ag[2] += q.z; ag[3] += q.w;
            q = redL[5 * 256 + u]; ag[4] += q.x; ag[5] += q.y; ag[6] += q.z; ag[7] += q.w;
            q = redL[6 * 256 + u]; ao[0] += q.x; ao[1] += q.y; ao[2] += q.z; ao[3] += q.w;
            q = redL[7 * 256 + u]; ao[4] += q.x; ao[5] += q.y; ao[6] += q.z; ao[7] += q.w;
#pragma unroll
            for (int r = 0; r < ROWS; ++r) {
                float iv = sigm(ai[r]), fv = sigm(af[r]);
                float gv = tanh_(ag[r]), ov = sigm(ao[r]);
                c1[r] = fmaf(fv, c1[r], iv * gv);
                h1L[u * ROWS + r] = ov * tanh_(c1[r]);
            }
        }
        __syncthreads();                       // b2: new h1 visible, redL free

        // ---- Phase B partials: kh0 = b1 + W_ih1@h1_new ; kh1 = W_hh1@h2_old ----
#pragma unroll
        for (int r = 0; r < ROWS; ++r) { ai[r] = b1i; af[r] = b1f; ag[r] = b1g; ao[r] = b1o; }
        {
            const float* src = (kh == 0) ? h1L : h2L;
            const int kwb = kh << 8;   // 0 or 256
#pragma unroll 4
            for (int k = 0; k < 256; ++k) {
                float4 w = W41[(kwb + k) * Hd + u];
                const float4 xa = *(const float4*)&src[k * ROWS];
                const float4 xb = *(const float4*)&src[k * ROWS + 4];
                float xr[8] = {xa.x, xa.y, xa.z, xa.w, xb.x, xb.y, xb.z, xb.w};
#pragma unroll
                for (int r = 0; r < ROWS; ++r) {
                    ai[r] = fmaf(xr[r], w.x, ai[r]); af[r] = fmaf(xr[r], w.y, af[r]);
                    ag[r] = fmaf(xr[r], w.z, ag[r]); ao[r] = fmaf(xr[r], w.w, ao[r]);
                }
            }
        }
        if (kh == 1) {
            redL[0 * 256 + u] = make_float4(ai[0], ai[1], ai[2], ai[3]);
            redL[1 * 256 + u] = make_float4(ai[4], ai[5], ai[6], ai[7]);
            redL[2 * 256 + u] = make_float4(af[0], af[1], af[2], af[3]);
            redL[3 * 256 + u] = make_float4(af[4], af[5], af[6], af[7]);
            redL[4 * 256 + u] = make_float4(ag[0], ag[1], ag[2], ag[3]);
            redL[5 * 256 + u] = make_float4(ag[4], ag[5], ag[6], ag[7]);
            redL[6 * 256 + u] = make_float4(ao[0], ao[1], ao[2], ao[3]);
            redL[7 * 256 + u] = make_float4(ao[4], ao[5], ao[6], ao[7]);
        }
        __syncthreads();                       // b3
        if (kh == 0) {
            float4 q;
            q = redL[0 * 256 + u]; ai[0] += q.x; ai[1] += q.y; ai[2] += q.z; ai[3] += q.w;
            q = redL[1 * 256 + u]; ai[4] += q.x; ai[5] += q.y; ai[6] += q.z; ai[7] += q.w;
            q = redL[2 * 256 + u]; af[0] += q.x; af[1] += q.y; af[2] += q.z; af[3] += q.w;
            q = redL[3 * 256 + u]; af[4] += q.x; af[5] += q.y; af[6] += q.z; af[7] += q.w;
            q = redL[4 * 256 + u]; ag[0] += q.x; ag[1] += q.y; ag[2] += q.z; ag[3] += q.w;
            q = redL[5 * 256 + u]; ag[4] += q.x; ag[5] += q.y; ag[6] += q.z; ag[7] += q.w;
            q = redL[6 * 256 + u]; ao[0] += q.x; ao[1] += q.y; ao[2] += q.z; ao[3] += q.w;
            q = redL[7 * 256 + u]; ao[4] += q.x; ao[5] += q.y; ao[6] += q.z; ao[7] += q.w;
#pragma unroll
            for (int r = 0; r < ROWS; ++r) {
                float iv = sigm(ai[r]), fv = sigm(af[r]);
                float gv = tanh_(ag[r]), ov = sigm(ao[r]);
                c2[r] = fmaf(fv, c2[r], iv * gv);
                h2L[u * ROWS + r] = ov * tanh_(c2[r]);
            }
        }
        __syncthreads();                       // b4: new h2 visible

        // ---- Phase C: mlp = relu(h2 @ W_out1.T + b_out1); 512 thr = (m, row) ----
        {
            const int m = t & 63;
            const int r = t >> 6;              // 0..7
            float a = bm;
#pragma unroll 4
            for (int k = 0; k < Hd; ++k)
                a = fmaf(h2L[k * ROWS + r], O1T[k * 64 + m], a);
            mlpL[r * 64 + m] = fmaxf(a, 0.f);
        }
        __syncthreads();                       // b5

        // ---- Phase C2: pred = mlp @ W_out2.T + b_out2 ; pos <- pred ----
        if (t < 2 * ROWS) {
            int r = t >> 1, o = t & 1;
            float a = b_out2[o];
#pragma unroll
            for (int k = 0; k < 64; ++k) a = fmaf(mlpL[r * 64 + k], Wout2[o * 64 + k], a);
            posL[o * ROWS + r] = a;
            out[((size_t)(row0 + r) * Tst + step) * 2 + o] = a;
        }
        __syncthreads();                       // b6
    }
}

// ---------------- launch ----------------
extern "C" void kernel_launch(void* const* d_in, const int* in_sizes, int n_in,
                              void* d_out, int out_size, void* d_ws, size_t ws_size,
                              hipStream_t stream) {
    const float* env    = (const float*)d_in[0];
    const float* hist   = (const float*)d_in[1];
    const float* goal   = (const float*)d_in[2];
    const float* cpos   = (const float*)d_in[3];
    const float* Wproj  = (const float*)d_in[4];
    const float* bproj  = (const float*)d_in[5];
    const float* Wih0   = (const float*)d_in[6];
    const float* Whh0   = (const float*)d_in[7];
    const float* bih0   = (const float*)d_in[8];
    const float* bhh0   = (const float*)d_in[9];
    const float* Wih1   = (const float*)d_in[10];
    const float* Whh1   = (const float*)d_in[11];
    const float* bih1   = (const float*)d_in[12];
    const float* bhh1   = (const float*)d_in[13];
    const float* Wout1  = (const float*)d_in[14];
    const float* bout1  = (const float*)d_in[15];
    const float* Wout2  = (const float*)d_in[16];
    const float* bout2  = (const float*)d_in[17];

    if (ws_size < (size_t)WS_FLOATS * sizeof(float)) return;
    float* ws = (float*)d_ws;

    prep_kernel<<<(WS_FLOATS + 255) / 256, 256, 0, stream>>>(
        Wproj, Wih0, Whh0, Wih1, Whh1, Wout1, ws);

    lstm_main<<<NBLK, NTHR, 0, stream>>>(
        env, hist, goal, cpos, bproj, bih0, bhh0, bih1, bhh1,
        bout1, bout2, Wout2, ws, (float*)d_out);
}